// Round 4
// baseline (191.062 us; speedup 1.0000x reference)
//
#include <hip/hip_runtime.h>
#include <hip/hip_bf16.h>
#include <math.h>

#define Bb 512
#define Tt 256
#define Cc 384
#define Hh 64

#define APAD 72    // a_lds / k_lds stride (shorts)
#define WPAD 72    // w_lds stride (shorts)
#define VTP  264   // vt_lds stride (shorts)
#define QBP  68    // Q bounce stride (shorts)
#define PST  40    // P tile stride (shorts)

typedef __attribute__((ext_vector_type(8))) short short8;
typedef __attribute__((ext_vector_type(4))) short short4_;
typedef __attribute__((ext_vector_type(4))) float float4_;

static __device__ __forceinline__ unsigned short f2bf(float f) {
  __hip_bfloat16 h = __float2bfloat16(f);
  return *reinterpret_cast<unsigned short*>(&h);
}

// ---------------- kernel 0: pack W into transposed bf16 wt[192][384] ----------------
__global__ void wtrans_kernel(const float* __restrict__ wq,
                              const float* __restrict__ wk,
                              const float* __restrict__ wv,
                              unsigned short* __restrict__ wt) {
  int n = blockIdx.x;
  int k = threadIdx.x;
  const float* w = (n < 64) ? wq : (n < 128) ? wk : wv;
  wt[n * Cc + k] = f2bf(w[k * Hh + (n & 63)]);
}

// ---------------- fused kernel: per-batch QKV projection + causal flash attn ----------------
// LDS (80,896 B -> 2 blocks/CU):
//   region1 [256][APAD] : phase A = x-chunk staging (a_lds); phase B/C = K (k_lds)
//   region2 [64][VTP]   : phase A = W staging (w_lds, 192*WPAD fits); phase B/C = V^T (vt_lds)
//   region3 8*16*PST    : phase B = Q bounce rounds; phase C = per-wave P tiles
__global__ __launch_bounds__(512, 4) void fused_kernel(
    const float* __restrict__ x, const unsigned short* __restrict__ wt,
    float* __restrict__ out) {
  __shared__ unsigned short lds[256 * APAD + 64 * VTP + 8 * 16 * PST];
  unsigned short* a_lds  = lds;
  unsigned short* k_lds  = lds;                       // alias (phase-disjoint)
  unsigned short* w_lds  = lds + 256 * APAD;
  unsigned short* vt_lds = lds + 256 * APAD;          // alias (phase-disjoint)
  unsigned short* r3     = lds + 256 * APAD + 64 * VTP;

  const int t = threadIdx.x;
  const int wid = t >> 6, lane = t & 63;
  const int fr = lane & 15, fg = lane >> 4;
  const int wr = wid >> 1, wc = wid & 1;   // 4x2 wave grid: 64 rows x 96 cols each
  const int b = blockIdx.x;
  const float* xb = x + (size_t)b * Tt * Cc;

  // ================= phase A: QKV = x[b] @ W  (M=256, N=192, K=384) =================
  float4_ acc[4][6];
#pragma unroll
  for (int i = 0; i < 4; i++)
#pragma unroll
    for (int j = 0; j < 6; j++) acc[i][j] = (float4_)0.f;

  float4_ av[8];
#pragma unroll
  for (int i = 0; i < 8; i++) {
    int f = i * 512 + t;
    av[i] = *(const float4_*)(xb + (f >> 4) * Cc + (f & 15) * 4);
  }

  for (int ks = 0; ks < 6; ks++) {
    if (ks) {   // barrier A: prev MFMA LDS reads done; av loads stay in flight
      asm volatile("s_waitcnt lgkmcnt(0)" ::: "memory");
      __builtin_amdgcn_s_barrier();
      __builtin_amdgcn_sched_barrier(0);
    }
    // stage A: prefetched f32 -> bf16 LDS (compiler inserts vmcnt wait at use)
#pragma unroll
    for (int i = 0; i < 8; i++) {
      int f = i * 512 + t;
      short4_ pk;
#pragma unroll
      for (int j = 0; j < 4; j++) pk[j] = (short)f2bf(av[i][j]);
      *(short4_*)(&a_lds[(f >> 4) * APAD + (f & 15) * 4]) = pk;
    }
    // stage W chunk 192x64 (L2-hot)
#pragma unroll
    for (int i = 0; i < 3; i++) {
      int id = t + i * 512;
      int n = id >> 3, sg = id & 7;
      short8 v = *(const short8*)(wt + n * Cc + ks * 64 + sg * 8);
      *(short8*)(&w_lds[n * WPAD + sg * 8]) = v;
    }
    // issue next x-chunk loads; NOT drained by the manual barrier below
    if (ks < 5) {
#pragma unroll
      for (int i = 0; i < 8; i++) {
        int f = i * 512 + t;
        av[i] = *(const float4_*)(xb + (f >> 4) * Cc + (ks + 1) * 64 + (f & 15) * 4);
      }
    }
    // barrier B: staging visible; only lgkm drained
    asm volatile("s_waitcnt lgkmcnt(0)" ::: "memory");
    __builtin_amdgcn_s_barrier();
    __builtin_amdgcn_sched_barrier(0);
#pragma unroll
    for (int kk = 0; kk < 2; kk++) {
      short8 af[4], bf[6];
#pragma unroll
      for (int mi = 0; mi < 4; mi++)
        af[mi] = *(const short8*)(&a_lds[(wr * 64 + mi * 16 + fr) * APAD + kk * 32 + fg * 8]);
#pragma unroll
      for (int ni = 0; ni < 6; ni++)
        bf[ni] = *(const short8*)(&w_lds[(wc * 96 + ni * 16 + fr) * WPAD + kk * 32 + fg * 8]);
#pragma unroll
      for (int mi = 0; mi < 4; mi++)
#pragma unroll
        for (int ni = 0; ni < 6; ni++)
          acc[mi][ni] = __builtin_amdgcn_mfma_f32_16x16x32_bf16(af[mi], bf[ni], acc[mi][ni], 0, 0, 0);
    }
  }

  __syncthreads();   // end phase A: all LDS reads done before aliased overwrite

  // ================= phase B: scatter K/V; bounce Q to registers =================
  // acc D-layout: row = wr*64 + mi*16 + fg*4 + r, col = wc*96 + ni*16 + fr
#pragma unroll
  for (int mi = 0; mi < 4; mi++) {
    int row0 = wr * 64 + mi * 16 + fg * 4;
#pragma unroll
    for (int ni = 0; ni < 6; ni++) {
      int col = wc * 96 + ni * 16 + fr;
      if (wc == 1 && ni >= 2) {          // V cols 128..191 -> V^T [h][seq]
        short4_ pk;
#pragma unroll
        for (int r = 0; r < 4; r++) pk[r] = (short)f2bf(acc[mi][ni][r]);
        *(short4_*)(&vt_lds[(col - 128) * VTP + row0]) = pk;
      } else if (!(wc == 0 && ni < 4)) { // K cols 64..127 -> [seq][h]
#pragma unroll
        for (int r = 0; r < 4; r++)
          k_lds[(row0 + r) * APAD + (col - 64)] = f2bf(acc[mi][ni][r]);
      }
    }
  }

  // Q bounce: 4 rounds through region3; each wave ends with A-frag-style Q regs
  short8 aqA0 = {}, aqA1 = {}, aqB0 = {}, aqB1 = {};
  const int qtA = wid, qtB = 15 - wid;   // balanced causal split (9 kt-steps each)
  for (int rd = 0; rd < 4; rd++) {
    if (rd) __syncthreads();            // previous round's consumers done
    if (wid == 2 * rd) {                // producer wave (wc==0, wr==rd): tiles rd*4+mi
#pragma unroll
      for (int mi = 0; mi < 4; mi++)
#pragma unroll
        for (int ni = 0; ni < 4; ni++)
#pragma unroll
          for (int r = 0; r < 4; r++)
            r3[(mi * 16 + fg * 4 + r) * QBP + ni * 16 + fr] = f2bf(acc[mi][ni][r]);
    }
    __syncthreads();
    if ((qtA >> 2) == rd) {
      int tl = qtA & 3;
      aqA0 = *(const short8*)(&r3[(tl * 16 + fr) * QBP + fg * 8]);
      aqA1 = *(const short8*)(&r3[(tl * 16 + fr) * QBP + 32 + fg * 8]);
    }
    if ((qtB >> 2) == rd) {
      int tl = qtB & 3;
      aqB0 = *(const short8*)(&r3[(tl * 16 + fr) * QBP + fg * 8]);
      aqB1 = *(const short8*)(&r3[(tl * 16 + fr) * QBP + 32 + fg * 8]);
    }
  }
  __syncthreads();   // bounce done before region3 becomes P tiles

  // ================= phase C: causal flash attn, swapped-operand layout =================
  unsigned short* pw = r3 + wid * 16 * PST;   // wave-private P tile [16 q][32 k]
  const float SC  = 0.05103103630798288f;     // 384^-0.5
  const float L2E = 1.4426950408889634f;

  auto run_tile = [&](int qt, short8 aq0, short8 aq1) {
    float4_ o[4] = {(float4_)0.f, (float4_)0.f, (float4_)0.f, (float4_)0.f};
    float m = -3.0e38f, l = 0.f;
    const int qg = qt * 16 + fr;   // this lane's q row
    int ktmax = qt >> 1;
    for (int kt = 0; kt <= ktmax; kt++) {
      // S^T = K . Q^T : lane holds q=fr, k = half*16 + fg*4 + r
      float4_ s0 = (float4_)0.f, s1 = (float4_)0.f;
      short8 k0 = *(const short8*)(&k_lds[(kt * 32 + fr) * APAD + fg * 8]);
      short8 k1 = *(const short8*)(&k_lds[(kt * 32 + 16 + fr) * APAD + fg * 8]);
      s0 = __builtin_amdgcn_mfma_f32_16x16x32_bf16(k0, aq0, s0, 0, 0, 0);
      s1 = __builtin_amdgcn_mfma_f32_16x16x32_bf16(k1, aq0, s1, 0, 0, 0);
      short8 k2 = *(const short8*)(&k_lds[(kt * 32 + fr) * APAD + 32 + fg * 8]);
      short8 k3 = *(const short8*)(&k_lds[(kt * 32 + 16 + fr) * APAD + 32 + fg * 8]);
      s0 = __builtin_amdgcn_mfma_f32_16x16x32_bf16(k2, aq1, s0, 0, 0, 0);
      s1 = __builtin_amdgcn_mfma_f32_16x16x32_bf16(k3, aq1, s1, 0, 0, 0);

      bool edge = (kt == ktmax);
      float vs[8];
#pragma unroll
      for (int r = 0; r < 4; r++) {
        int kg0 = kt * 32 + fg * 4 + r;
        float a0 = s0[r] * SC, a1 = s1[r] * SC;
        if (edge && kg0 > qg)      a0 = -3.0e38f;
        if (edge && kg0 + 16 > qg) a1 = -3.0e38f;
        vs[r] = a0; vs[4 + r] = a1;
      }
      // lane-local 8-way max + 2-level butterfly (fg groups share q=fr)
      float mx = fmaxf(fmaxf(fmaxf(vs[0], vs[1]), fmaxf(vs[2], vs[3])),
                       fmaxf(fmaxf(vs[4], vs[5]), fmaxf(vs[6], vs[7])));
      mx = fmaxf(mx, __shfl_xor(mx, 16));
      mx = fmaxf(mx, __shfl_xor(mx, 32));
      float mn = fmaxf(m, mx);
      float scal = exp2f((m - mn) * L2E);
      float p[8]; float ps = 0.f;
#pragma unroll
      for (int j = 0; j < 8; j++) { p[j] = exp2f((vs[j] - mn) * L2E); ps += p[j]; }
      ps += __shfl_xor(ps, 16);
      ps += __shfl_xor(ps, 32);
      l = l * scal + ps;
      m = mn;
#pragma unroll
      for (int nt = 0; nt < 4; nt++) o[nt] *= scal;   // lane-local rescale (O^T: col=q=fr)

      // P -> p_lds [q=fr][k]: two b64 writes, one b128 read as B-frag
      short4_ pk0, pk1;
#pragma unroll
      for (int r = 0; r < 4; r++) { pk0[r] = (short)f2bf(p[r]); pk1[r] = (short)f2bf(p[4 + r]); }
      *(short4_*)(&pw[fr * PST + fg * 4]) = pk0;
      *(short4_*)(&pw[fr * PST + 16 + fg * 4]) = pk1;
      asm volatile("s_waitcnt lgkmcnt(0)" ::: "memory");
      __builtin_amdgcn_sched_barrier(0);
      short8 pb = *(const short8*)(&pw[fr * PST + fg * 8]);
      // O^T += V^T . P : A-frag = V^T rows (h=nt*16+fr), B-frag = P
#pragma unroll
      for (int nt = 0; nt < 4; nt++) {
        short8 bv = *(const short8*)(&vt_lds[(nt * 16 + fr) * VTP + kt * 32 + fg * 8]);
        o[nt] = __builtin_amdgcn_mfma_f32_16x16x32_bf16(bv, pb, o[nt], 0, 0, 0);
      }
    }
    // epilogue: O^T[h=nt*16+fg*4+r][q=fr] / l  -> coalesced float4 stores
    float inv = 1.f / l;
#pragma unroll
    for (int nt = 0; nt < 4; nt++) {
      float4_ ov = o[nt] * inv;
      *(float4_*)(&out[((size_t)b * Tt + qt * 16 + fr) * Hh + nt * 16 + fg * 4]) = ov;
    }
  };
  run_tile(qtA, aqA0, aqA1);
  run_tile(qtB, aqB0, aqB1);
}

extern "C" void kernel_launch(void* const* d_in, const int* in_sizes, int n_in,
                              void* d_out, int out_size, void* d_ws, size_t ws_size,
                              hipStream_t stream) {
  const float* x  = (const float*)d_in[0];
  const float* wq = (const float*)d_in[1];
  const float* wk = (const float*)d_in[2];
  const float* wv = (const float*)d_in[3];
  unsigned short* wt = (unsigned short*)d_ws;   // 192*384 bf16
  float* out = (float*)d_out;

  hipLaunchKernelGGL(wtrans_kernel, dim3(192), dim3(384), 0, stream, wq, wk, wv, wt);
  hipLaunchKernelGGL(fused_kernel,  dim3(Bb),  dim3(512), 0, stream, x, wt, out);
}

// Round 5
// 69.628 us; speedup vs baseline: 2.7440x; 2.7440x over previous
//
#include <hip/hip_runtime.h>
#include <hip/hip_bf16.h>
#include <math.h>

#define Bb 512
#define Tt 256
#define Cc 384
#define Hh 64

#define APAD 72    // a_lds / k_lds stride (shorts)
#define WPAD 72    // w_lds stride (shorts)
#define VTP  264   // vt_lds stride (shorts)
#define QBP  68    // Q bounce stride (shorts)
#define PST  40    // P tile stride (shorts)

typedef __attribute__((ext_vector_type(8))) short short8;
typedef __attribute__((ext_vector_type(4))) short short4_;
typedef __attribute__((ext_vector_type(4))) float float4_;

static __device__ __forceinline__ unsigned short f2bf(float f) {
  __hip_bfloat16 h = __float2bfloat16(f);
  return *reinterpret_cast<unsigned short*>(&h);
}

// ---------------- kernel 0: pack W into transposed bf16 wt[192][384] ----------------
__global__ void wtrans_kernel(const float* __restrict__ wq,
                              const float* __restrict__ wk,
                              const float* __restrict__ wv,
                              unsigned short* __restrict__ wt) {
  int n = blockIdx.x;
  int k = threadIdx.x;
  const float* w = (n < 64) ? wq : (n < 128) ? wk : wv;
  wt[n * Cc + k] = f2bf(w[k * Hh + (n & 63)]);
}

// ---------------- fused kernel: per-batch QKV projection + causal flash attn ----------------
// LDS (80,896 B):
//   region1 [256][APAD] : phase A = x-chunk staging (a_lds); phase B/C = K (k_lds)
//   region2 [64][VTP]   : phase A = W staging (w_lds, 192*WPAD fits); phase B/C = V^T (vt_lds)
//   region3 8*16*PST    : phase B = Q bounce rounds; phase C = per-wave P tiles
// launch_bounds (512,2): 256-reg budget. acc[4][6]=96 + av[8]=32 + working set
// ~= 220 regs — MUST NOT be capped tighter (512,4 spilled acc to scratch: R4).
__global__ __launch_bounds__(512, 2) void fused_kernel(
    const float* __restrict__ x, const unsigned short* __restrict__ wt,
    float* __restrict__ out) {
  __shared__ unsigned short lds[256 * APAD + 64 * VTP + 8 * 16 * PST];
  unsigned short* a_lds  = lds;
  unsigned short* k_lds  = lds;                       // alias (phase-disjoint)
  unsigned short* w_lds  = lds + 256 * APAD;
  unsigned short* vt_lds = lds + 256 * APAD;          // alias (phase-disjoint)
  unsigned short* r3     = lds + 256 * APAD + 64 * VTP;

  const int t = threadIdx.x;
  const int wid = t >> 6, lane = t & 63;
  const int fr = lane & 15, fg = lane >> 4;
  const int wr = wid >> 1, wc = wid & 1;   // 4x2 wave grid: 64 rows x 96 cols each
  const int b = blockIdx.x;
  const float* xb = x + (size_t)b * Tt * Cc;

  // ================= phase A: QKV = x[b] @ W  (M=256, N=192, K=384) =================
  float4_ acc[4][6];
#pragma unroll
  for (int i = 0; i < 4; i++)
#pragma unroll
    for (int j = 0; j < 6; j++) acc[i][j] = (float4_)0.f;

  float4_ av[8];
#pragma unroll
  for (int i = 0; i < 8; i++) {
    int f = i * 512 + t;
    av[i] = *(const float4_*)(xb + (f >> 4) * Cc + (f & 15) * 4);
  }

  for (int ks = 0; ks < 6; ks++) {
    if (ks) {   // barrier A: prev MFMA LDS reads done; av loads stay in flight
      asm volatile("s_waitcnt lgkmcnt(0)" ::: "memory");
      __builtin_amdgcn_s_barrier();
      __builtin_amdgcn_sched_barrier(0);
    }
    // stage A: prefetched f32 -> bf16 LDS (compiler inserts vmcnt wait at use)
#pragma unroll
    for (int i = 0; i < 8; i++) {
      int f = i * 512 + t;
      short4_ pk;
#pragma unroll
      for (int j = 0; j < 4; j++) pk[j] = (short)f2bf(av[i][j]);
      *(short4_*)(&a_lds[(f >> 4) * APAD + (f & 15) * 4]) = pk;
    }
    // stage W chunk 192x64 (L2-hot)
#pragma unroll
    for (int i = 0; i < 3; i++) {
      int id = t + i * 512;
      int n = id >> 3, sg = id & 7;
      short8 v = *(const short8*)(wt + n * Cc + ks * 64 + sg * 8);
      *(short8*)(&w_lds[n * WPAD + sg * 8]) = v;
    }
    // issue next x-chunk loads; NOT drained by the manual barrier below
    if (ks < 5) {
#pragma unroll
      for (int i = 0; i < 8; i++) {
        int f = i * 512 + t;
        av[i] = *(const float4_*)(xb + (f >> 4) * Cc + (ks + 1) * 64 + (f & 15) * 4);
      }
    }
    // barrier B: staging visible; only lgkm drained
    asm volatile("s_waitcnt lgkmcnt(0)" ::: "memory");
    __builtin_amdgcn_s_barrier();
    __builtin_amdgcn_sched_barrier(0);
#pragma unroll
    for (int kk = 0; kk < 2; kk++) {
      short8 af[4], bf[6];
#pragma unroll
      for (int mi = 0; mi < 4; mi++)
        af[mi] = *(const short8*)(&a_lds[(wr * 64 + mi * 16 + fr) * APAD + kk * 32 + fg * 8]);
#pragma unroll
      for (int ni = 0; ni < 6; ni++)
        bf[ni] = *(const short8*)(&w_lds[(wc * 96 + ni * 16 + fr) * WPAD + kk * 32 + fg * 8]);
#pragma unroll
      for (int mi = 0; mi < 4; mi++)
#pragma unroll
        for (int ni = 0; ni < 6; ni++)
          acc[mi][ni] = __builtin_amdgcn_mfma_f32_16x16x32_bf16(af[mi], bf[ni], acc[mi][ni], 0, 0, 0);
    }
  }

  __syncthreads();   // end phase A: all LDS reads done before aliased overwrite

  // ================= phase B: scatter K/V; bounce Q to registers =================
  // acc D-layout: row = wr*64 + mi*16 + fg*4 + r, col = wc*96 + ni*16 + fr
#pragma unroll
  for (int mi = 0; mi < 4; mi++) {
    int row0 = wr * 64 + mi * 16 + fg * 4;
#pragma unroll
    for (int ni = 0; ni < 6; ni++) {
      int col = wc * 96 + ni * 16 + fr;
      if (wc == 1 && ni >= 2) {          // V cols 128..191 -> V^T [h][seq]
        short4_ pk;
#pragma unroll
        for (int r = 0; r < 4; r++) pk[r] = (short)f2bf(acc[mi][ni][r]);
        *(short4_*)(&vt_lds[(col - 128) * VTP + row0]) = pk;
      } else if (!(wc == 0 && ni < 4)) { // K cols 64..127 -> [seq][h]
#pragma unroll
        for (int r = 0; r < 4; r++)
          k_lds[(row0 + r) * APAD + (col - 64)] = f2bf(acc[mi][ni][r]);
      }
    }
  }

  // Q bounce: 4 rounds through region3; each wave ends with A-frag-style Q regs
  short8 aqA0 = {}, aqA1 = {}, aqB0 = {}, aqB1 = {};
  const int qtA = wid, qtB = 15 - wid;   // balanced causal split (9 kt-steps each)
  for (int rd = 0; rd < 4; rd++) {
    if (rd) __syncthreads();            // previous round's consumers done
    if (wid == 2 * rd) {                // producer wave (wc==0, wr==rd): tiles rd*4+mi
#pragma unroll
      for (int mi = 0; mi < 4; mi++)
#pragma unroll
        for (int ni = 0; ni < 4; ni++)
#pragma unroll
          for (int r = 0; r < 4; r++)
            r3[(mi * 16 + fg * 4 + r) * QBP + ni * 16 + fr] = f2bf(acc[mi][ni][r]);
    }
    __syncthreads();
    if ((qtA >> 2) == rd) {
      int tl = qtA & 3;
      aqA0 = *(const short8*)(&r3[(tl * 16 + fr) * QBP + fg * 8]);
      aqA1 = *(const short8*)(&r3[(tl * 16 + fr) * QBP + 32 + fg * 8]);
    }
    if ((qtB >> 2) == rd) {
      int tl = qtB & 3;
      aqB0 = *(const short8*)(&r3[(tl * 16 + fr) * QBP + fg * 8]);
      aqB1 = *(const short8*)(&r3[(tl * 16 + fr) * QBP + 32 + fg * 8]);
    }
  }
  __syncthreads();   // bounce done before region3 becomes P tiles

  // ================= phase C: causal flash attn, swapped-operand layout =================
  unsigned short* pw = r3 + wid * 16 * PST;   // wave-private P tile [16 q][32 k]
  const float SC  = 0.05103103630798288f;     // 384^-0.5
  const float L2E = 1.4426950408889634f;

  auto run_tile = [&](int qt, short8 aq0, short8 aq1) {
    float4_ o[4] = {(float4_)0.f, (float4_)0.f, (float4_)0.f, (float4_)0.f};
    float m = -3.0e38f, l = 0.f;
    const int qg = qt * 16 + fr;   // this lane's q row
    int ktmax = qt >> 1;
    for (int kt = 0; kt <= ktmax; kt++) {
      // S^T = K . Q^T : lane holds q=fr, k = half*16 + fg*4 + r
      float4_ s0 = (float4_)0.f, s1 = (float4_)0.f;
      short8 k0 = *(const short8*)(&k_lds[(kt * 32 + fr) * APAD + fg * 8]);
      short8 k1 = *(const short8*)(&k_lds[(kt * 32 + 16 + fr) * APAD + fg * 8]);
      s0 = __builtin_amdgcn_mfma_f32_16x16x32_bf16(k0, aq0, s0, 0, 0, 0);
      s1 = __builtin_amdgcn_mfma_f32_16x16x32_bf16(k1, aq0, s1, 0, 0, 0);
      short8 k2 = *(const short8*)(&k_lds[(kt * 32 + fr) * APAD + 32 + fg * 8]);
      short8 k3 = *(const short8*)(&k_lds[(kt * 32 + 16 + fr) * APAD + 32 + fg * 8]);
      s0 = __builtin_amdgcn_mfma_f32_16x16x32_bf16(k2, aq1, s0, 0, 0, 0);
      s1 = __builtin_amdgcn_mfma_f32_16x16x32_bf16(k3, aq1, s1, 0, 0, 0);

      bool edge = (kt == ktmax);
      float vs[8];
#pragma unroll
      for (int r = 0; r < 4; r++) {
        int kg0 = kt * 32 + fg * 4 + r;
        float a0 = s0[r] * SC, a1 = s1[r] * SC;
        if (edge && kg0 > qg)      a0 = -3.0e38f;
        if (edge && kg0 + 16 > qg) a1 = -3.0e38f;
        vs[r] = a0; vs[4 + r] = a1;
      }
      // lane-local 8-way max + 2-level butterfly (fg groups share q=fr)
      float mx = fmaxf(fmaxf(fmaxf(vs[0], vs[1]), fmaxf(vs[2], vs[3])),
                       fmaxf(fmaxf(vs[4], vs[5]), fmaxf(vs[6], vs[7])));
      mx = fmaxf(mx, __shfl_xor(mx, 16));
      mx = fmaxf(mx, __shfl_xor(mx, 32));
      float mn = fmaxf(m, mx);
      float scal = exp2f((m - mn) * L2E);
      float p[8]; float ps = 0.f;
#pragma unroll
      for (int j = 0; j < 8; j++) { p[j] = exp2f((vs[j] - mn) * L2E); ps += p[j]; }
      ps += __shfl_xor(ps, 16);
      ps += __shfl_xor(ps, 32);
      l = l * scal + ps;
      m = mn;
#pragma unroll
      for (int nt = 0; nt < 4; nt++) o[nt] *= scal;   // lane-local rescale (O^T: col=q=fr)

      // P -> p_lds [q=fr][k]: two b64 writes, one b128 read as B-frag
      short4_ pk0, pk1;
#pragma unroll
      for (int r = 0; r < 4; r++) { pk0[r] = (short)f2bf(p[r]); pk1[r] = (short)f2bf(p[4 + r]); }
      *(short4_*)(&pw[fr * PST + fg * 4]) = pk0;
      *(short4_*)(&pw[fr * PST + 16 + fg * 4]) = pk1;
      asm volatile("s_waitcnt lgkmcnt(0)" ::: "memory");
      __builtin_amdgcn_sched_barrier(0);
      short8 pb = *(const short8*)(&pw[fr * PST + fg * 8]);
      // O^T += V^T . P : A-frag = V^T rows (h=nt*16+fr), B-frag = P
#pragma unroll
      for (int nt = 0; nt < 4; nt++) {
        short8 bv = *(const short8*)(&vt_lds[(nt * 16 + fr) * VTP + kt * 32 + fg * 8]);
        o[nt] = __builtin_amdgcn_mfma_f32_16x16x32_bf16(bv, pb, o[nt], 0, 0, 0);
      }
    }
    // epilogue: O^T[h=nt*16+fg*4+r][q=fr] / l  -> coalesced float4 stores
    float inv = 1.f / l;
#pragma unroll
    for (int nt = 0; nt < 4; nt++) {
      float4_ ov = o[nt] * inv;
      *(float4_*)(&out[((size_t)b * Tt + qt * 16 + fr) * Hh + nt * 16 + fg * 4]) = ov;
    }
  };
  run_tile(qtA, aqA0, aqA1);
  run_tile(qtB, aqB0, aqB1);
}

extern "C" void kernel_launch(void* const* d_in, const int* in_sizes, int n_in,
                              void* d_out, int out_size, void* d_ws, size_t ws_size,
                              hipStream_t stream) {
  const float* x  = (const float*)d_in[0];
  const float* wq = (const float*)d_in[1];
  const float* wk = (const float*)d_in[2];
  const float* wv = (const float*)d_in[3];
  unsigned short* wt = (unsigned short*)d_ws;   // 192*384 bf16
  float* out = (float*)d_out;

  hipLaunchKernelGGL(wtrans_kernel, dim3(192), dim3(384), 0, stream, wq, wk, wv, wt);
  hipLaunchKernelGGL(fused_kernel,  dim3(Bb),  dim3(512), 0, stream, x, wt, out);
}

// Round 6
// 69.372 us; speedup vs baseline: 2.7542x; 1.0037x over previous
//
#include <hip/hip_runtime.h>
#include <hip/hip_bf16.h>
#include <math.h>

#define Bb 512
#define Tt 256
#define Cc 384
#define Hh 64

#define APAD 72    // a_lds / k_lds stride (shorts)
#define WPAD 72    // w_lds stride (shorts)
#define VTP  264   // vt_lds stride (shorts)
#define QBP  72    // q_lds stride (shorts)
#define PST  40    // P tile stride (shorts)

typedef __attribute__((ext_vector_type(8))) short short8;
typedef __attribute__((ext_vector_type(4))) short short4_;
typedef __attribute__((ext_vector_type(4))) float float4_;

static __device__ __forceinline__ unsigned short f2bf(float f) {
  __hip_bfloat16 h = __float2bfloat16(f);
  return *reinterpret_cast<unsigned short*>(&h);
}

// ---------------- kernel 0: pack W into transposed bf16 wt[192][384] ----------------
// 24 blocks x 256t; each handles 8 output rows of one w via LDS transpose.
// Coalesced reads (32B segments) + coalesced u16 writes (R5's version read
// 256B-strided columns per lane).
__global__ __launch_bounds__(256) void wtrans_kernel(
    const float* __restrict__ wq, const float* __restrict__ wk,
    const float* __restrict__ wv, unsigned short* __restrict__ wt) {
  __shared__ float tl[384 * 8];
  const int blk = blockIdx.x;
  const int wsel = blk >> 3, n0 = (blk & 7) * 8;
  const float* w = (wsel == 0) ? wq : (wsel == 1) ? wk : wv;
  const int t = threadIdx.x;
#pragma unroll
  for (int i = 0; i < 3; i++) {          // 384 rows x 2 float4
    int id = i * 256 + t;
    int row = id >> 1, sg = id & 1;
    float4_ v = *(const float4_*)(w + row * Hh + n0 + sg * 4);
    *(float4_*)(&tl[row * 8 + sg * 4]) = v;
  }
  __syncthreads();
#pragma unroll
  for (int i = 0; i < 12; i++) {         // 8 rows x 384 cols out
    int id = i * 256 + t;
    int n = id / 384, k = id % 384;
    wt[(size_t)(wsel * 64 + n0 + n) * Cc + k] = f2bf(tl[k * 8 + n]);
  }
}

// ---------------- fused kernel: per-batch QKV projection + causal flash attn ----------------
// LDS map (117,760 B; 1 block/CU — VGPR-bound anyway):
//   region1 [256][APAD] : phase A = x-chunk bf16 staging; phase B/C = K
//   region2 [64][VTP]   : phase A = W staging (192*WPAD fits); phase B/C = V^T
//   region3 [256][QBP]  : phase B/C = Q (kills the R5 Q-bounce rounds)
//   region4 8*16*PST    : phase C = per-wave P tiles
// launch_bounds (512,2): 256-reg budget. acc 96 + av 64 (2-deep) + misc ~= 248.
// MUST NOT cap tighter (R4: (512,4) spilled acc, 2.7x regression).
__global__ __launch_bounds__(512, 2) void fused_kernel(
    const float* __restrict__ x, const unsigned short* __restrict__ wt,
    float* __restrict__ out) {
  __shared__ unsigned short lds[256 * APAD + 64 * VTP + 256 * QBP + 8 * 16 * PST];
  unsigned short* a_lds  = lds;
  unsigned short* k_lds  = lds;                        // alias (phase-disjoint)
  unsigned short* w_lds  = lds + 256 * APAD;
  unsigned short* vt_lds = lds + 256 * APAD;           // alias (phase-disjoint)
  unsigned short* q_lds  = lds + 256 * APAD + 64 * VTP;
  unsigned short* r3     = lds + 256 * APAD + 64 * VTP + 256 * QBP;

  const int t = threadIdx.x;
  const int wid = t >> 6, lane = t & 63;
  const int fr = lane & 15, fg = lane >> 4;
  const int wr = wid >> 1, wc = wid & 1;   // 4x2 wave grid: 64 rows x 96 cols each
  const int b = blockIdx.x;
  const float* xb = x + (size_t)b * Tt * Cc;

  // ================= phase A: QKV = x[b] @ W  (M=256, N=192, K=384) =================
  float4_ acc[4][6];
#pragma unroll
  for (int i = 0; i < 4; i++)
#pragma unroll
    for (int j = 0; j < 6; j++) acc[i][j] = (float4_)0.f;

  // 2-deep register prefetch: chunk k's loads get a full iteration in flight
  float4_ av[2][8];
#pragma unroll
  for (int buf = 0; buf < 2; buf++)
#pragma unroll
    for (int i = 0; i < 8; i++) {
      int f = i * 512 + t;
      av[buf][i] = *(const float4_*)(xb + (f >> 4) * Cc + buf * 64 + (f & 15) * 4);
    }

#pragma unroll
  for (int ks = 0; ks < 6; ks++) {
    const int cur = ks & 1;
    if (ks) {   // barrier A: prev MFMA LDS reads done; vm loads stay in flight
      asm volatile("s_waitcnt lgkmcnt(0)" ::: "memory");
      __builtin_amdgcn_s_barrier();
      __builtin_amdgcn_sched_barrier(0);
    }
    // W chunk loads first (L2-hot): latency hides under the av vmcnt wait below
    short8 wv[3];
#pragma unroll
    for (int i = 0; i < 3; i++) {
      int id = t + i * 512;
      wv[i] = *(const short8*)(wt + (id >> 3) * Cc + ks * 64 + (id & 7) * 8);
    }
    // stage A: prefetched f32 -> bf16 LDS (compiler emits vmcnt wait here)
#pragma unroll
    for (int i = 0; i < 8; i++) {
      int f = i * 512 + t;
      short4_ pk;
#pragma unroll
      for (int j = 0; j < 4; j++) pk[j] = (short)f2bf(av[cur][i][j]);
      *(short4_*)(&a_lds[(f >> 4) * APAD + (f & 15) * 4]) = pk;
    }
    // issue chunk ks+2 into the buffer just consumed
    if (ks < 4) {
#pragma unroll
      for (int i = 0; i < 8; i++) {
        int f = i * 512 + t;
        av[cur][i] = *(const float4_*)(xb + (f >> 4) * Cc + (ks + 2) * 64 + (f & 15) * 4);
      }
    }
    // W store
#pragma unroll
    for (int i = 0; i < 3; i++) {
      int id = t + i * 512;
      *(short8*)(&w_lds[(id >> 3) * WPAD + (id & 7) * 8]) = wv[i];
    }
    // barrier B: staging visible; only lgkm drained (av loads NOT drained)
    asm volatile("s_waitcnt lgkmcnt(0)" ::: "memory");
    __builtin_amdgcn_s_barrier();
    __builtin_amdgcn_sched_barrier(0);
#pragma unroll
    for (int kk = 0; kk < 2; kk++) {
      short8 af[4], bf[6];
#pragma unroll
      for (int mi = 0; mi < 4; mi++)
        af[mi] = *(const short8*)(&a_lds[(wr * 64 + mi * 16 + fr) * APAD + kk * 32 + fg * 8]);
#pragma unroll
      for (int ni = 0; ni < 6; ni++)
        bf[ni] = *(const short8*)(&w_lds[(wc * 96 + ni * 16 + fr) * WPAD + kk * 32 + fg * 8]);
#pragma unroll
      for (int mi = 0; mi < 4; mi++)
#pragma unroll
        for (int ni = 0; ni < 6; ni++)
          acc[mi][ni] = __builtin_amdgcn_mfma_f32_16x16x32_bf16(af[mi], bf[ni], acc[mi][ni], 0, 0, 0);
    }
  }

  __syncthreads();   // end phase A: all LDS reads done before aliased overwrite

  // ================= phase B: scatter Q/K/V into attention layouts =================
  // acc D-layout: row = wr*64 + mi*16 + fg*4 + r, col = wc*96 + ni*16 + fr
#pragma unroll
  for (int mi = 0; mi < 4; mi++) {
    int row0 = wr * 64 + mi * 16 + fg * 4;
#pragma unroll
    for (int ni = 0; ni < 6; ni++) {
      int col = wc * 96 + ni * 16 + fr;
      if (wc == 1 && ni >= 2) {          // V cols 128..191 -> V^T [h][seq]
        short4_ pk;
#pragma unroll
        for (int r = 0; r < 4; r++) pk[r] = (short)f2bf(acc[mi][ni][r]);
        *(short4_*)(&vt_lds[(col - 128) * VTP + row0]) = pk;
      } else if (wc == 0 && ni < 4) {    // Q cols 0..63 -> [seq][h]
#pragma unroll
        for (int r = 0; r < 4; r++)
          q_lds[(row0 + r) * QBP + col] = f2bf(acc[mi][ni][r]);
      } else {                           // K cols 64..127 -> [seq][h]
#pragma unroll
        for (int r = 0; r < 4; r++)
          k_lds[(row0 + r) * APAD + (col - 64)] = f2bf(acc[mi][ni][r]);
      }
    }
  }
  __syncthreads();

  // ================= phase C: causal flash attn, swapped-operand layout =================
  unsigned short* pw = r3 + wid * 16 * PST;   // wave-private P tile [16 q][32 k]
  const float SC  = 0.05103103630798288f;     // 384^-0.5
  const float L2E = 1.4426950408889634f;

  auto run_tile = [&](int qt) {
    short8 aq0 = *(const short8*)(&q_lds[(qt * 16 + fr) * QBP + fg * 8]);
    short8 aq1 = *(const short8*)(&q_lds[(qt * 16 + fr) * QBP + 32 + fg * 8]);
    float4_ o[4] = {(float4_)0.f, (float4_)0.f, (float4_)0.f, (float4_)0.f};
    float m = -3.0e38f, l = 0.f;
    const int qg = qt * 16 + fr;   // this lane's q row
    const int ktmax = qt >> 1;
    // preload kt=0 fragments (K and V^T)
    short8 kf0 = *(const short8*)(&k_lds[fr * APAD + fg * 8]);
    short8 kf1 = *(const short8*)(&k_lds[(16 + fr) * APAD + fg * 8]);
    short8 kf2 = *(const short8*)(&k_lds[fr * APAD + 32 + fg * 8]);
    short8 kf3 = *(const short8*)(&k_lds[(16 + fr) * APAD + 32 + fg * 8]);
    short8 bv0 = *(const short8*)(&vt_lds[fr * VTP + fg * 8]);
    short8 bv1 = *(const short8*)(&vt_lds[(16 + fr) * VTP + fg * 8]);
    short8 bv2 = *(const short8*)(&vt_lds[(32 + fr) * VTP + fg * 8]);
    short8 bv3 = *(const short8*)(&vt_lds[(48 + fr) * VTP + fg * 8]);
    for (int kt = 0; kt <= ktmax; kt++) {
      // S^T = K . Q^T : lane holds q=fr, k = half*16 + fg*4 + r
      float4_ s0 = (float4_)0.f, s1 = (float4_)0.f;
      s0 = __builtin_amdgcn_mfma_f32_16x16x32_bf16(kf0, aq0, s0, 0, 0, 0);
      s1 = __builtin_amdgcn_mfma_f32_16x16x32_bf16(kf1, aq0, s1, 0, 0, 0);
      s0 = __builtin_amdgcn_mfma_f32_16x16x32_bf16(kf2, aq1, s0, 0, 0, 0);
      s1 = __builtin_amdgcn_mfma_f32_16x16x32_bf16(kf3, aq1, s1, 0, 0, 0);
      // reload K frags for kt+1 (kf consumed); latency hides under softmax
      if (kt < ktmax) {
        int kb = (kt + 1) * 32;
        kf0 = *(const short8*)(&k_lds[(kb + fr) * APAD + fg * 8]);
        kf1 = *(const short8*)(&k_lds[(kb + 16 + fr) * APAD + fg * 8]);
        kf2 = *(const short8*)(&k_lds[(kb + fr) * APAD + 32 + fg * 8]);
        kf3 = *(const short8*)(&k_lds[(kb + 16 + fr) * APAD + 32 + fg * 8]);
      }
      bool edge = (kt == ktmax);
      float vs[8];
#pragma unroll
      for (int r = 0; r < 4; r++) {
        int kg0 = kt * 32 + fg * 4 + r;
        float a0 = s0[r] * SC, a1 = s1[r] * SC;
        if (edge && kg0 > qg)      a0 = -3.0e38f;
        if (edge && kg0 + 16 > qg) a1 = -3.0e38f;
        vs[r] = a0; vs[4 + r] = a1;
      }
      // lane-local 8-way max + 2-level butterfly (fg groups share q=fr)
      float mx = fmaxf(fmaxf(fmaxf(vs[0], vs[1]), fmaxf(vs[2], vs[3])),
                       fmaxf(fmaxf(vs[4], vs[5]), fmaxf(vs[6], vs[7])));
      mx = fmaxf(mx, __shfl_xor(mx, 16));
      mx = fmaxf(mx, __shfl_xor(mx, 32));
      // defer-rescale (T13, THR=8): skip O/l rescale when max growth is small
      if (!__all(mx - m <= 8.0f)) {
        float mn = fmaxf(m, mx);
        float scal = exp2f((m - mn) * L2E);
        l *= scal;
#pragma unroll
        for (int nt = 0; nt < 4; nt++) o[nt] *= scal;
        m = mn;
      }
      float p[8]; float ps = 0.f;
#pragma unroll
      for (int j = 0; j < 8; j++) { p[j] = exp2f((vs[j] - m) * L2E); ps += p[j]; }
      ps += __shfl_xor(ps, 16);
      ps += __shfl_xor(ps, 32);
      l += ps;

      // P -> p_lds [q=fr][k]: two b64 writes, one b128 read as B-frag
      short4_ pk0, pk1;
#pragma unroll
      for (int r = 0; r < 4; r++) { pk0[r] = (short)f2bf(p[r]); pk1[r] = (short)f2bf(p[4 + r]); }
      *(short4_*)(&pw[fr * PST + fg * 4]) = pk0;
      *(short4_*)(&pw[fr * PST + 16 + fg * 4]) = pk1;
      asm volatile("s_waitcnt lgkmcnt(0)" ::: "memory");
      __builtin_amdgcn_sched_barrier(0);
      short8 pb = *(const short8*)(&pw[fr * PST + fg * 8]);
      // O^T += V^T . P : A-frag = V^T rows (h=nt*16+fr), B-frag = P
      o[0] = __builtin_amdgcn_mfma_f32_16x16x32_bf16(bv0, pb, o[0], 0, 0, 0);
      o[1] = __builtin_amdgcn_mfma_f32_16x16x32_bf16(bv1, pb, o[1], 0, 0, 0);
      o[2] = __builtin_amdgcn_mfma_f32_16x16x32_bf16(bv2, pb, o[2], 0, 0, 0);
      o[3] = __builtin_amdgcn_mfma_f32_16x16x32_bf16(bv3, pb, o[3], 0, 0, 0);
      // reload V^T frags for kt+1 (bv consumed); latency hides under next QK+softmax
      if (kt < ktmax) {
        int kb = (kt + 1) * 32;
        bv0 = *(const short8*)(&vt_lds[fr * VTP + kb + fg * 8]);
        bv1 = *(const short8*)(&vt_lds[(16 + fr) * VTP + kb + fg * 8]);
        bv2 = *(const short8*)(&vt_lds[(32 + fr) * VTP + kb + fg * 8]);
        bv3 = *(const short8*)(&vt_lds[(48 + fr) * VTP + kb + fg * 8]);
      }
    }
    // epilogue: O^T[h=nt*16+fg*4+r][q=fr] / l  -> coalesced float4 stores
    float inv = 1.f / l;
#pragma unroll
    for (int nt = 0; nt < 4; nt++) {
      float4_ ov = o[nt] * inv;
      *(float4_*)(&out[((size_t)b * Tt + qt * 16 + fr) * Hh + nt * 16 + fg * 4]) = ov;
    }
  };
  run_tile(wid);        // balanced causal split: 9 kt-steps per wave total
  run_tile(15 - wid);
}

extern "C" void kernel_launch(void* const* d_in, const int* in_sizes, int n_in,
                              void* d_out, int out_size, void* d_ws, size_t ws_size,
                              hipStream_t stream) {
  const float* x  = (const float*)d_in[0];
  const float* wq = (const float*)d_in[1];
  const float* wk = (const float*)d_in[2];
  const float* wv = (const float*)d_in[3];
  unsigned short* wt = (unsigned short*)d_ws;   // 192*384 bf16
  float* out = (float*)d_out;

  hipLaunchKernelGGL(wtrans_kernel, dim3(24), dim3(256), 0, stream, wq, wk, wv, wt);
  hipLaunchKernelGGL(fused_kernel,  dim3(Bb), dim3(512), 0, stream, x, wt, out);
}